// Round 1
// baseline (624.863 us; speedup 1.0000x reference)
//
#include <hip/hip_runtime.h>
#include <hip/hip_bf16.h>

// Problem: N=8192 nodes, DIN=DOUT=256.
// out0 = relu( diag(d) (A+I) diag(d) (x @ W^T) ),  d_i = rsqrt(1 + #(A_ij>eps))
// out1 = A (verbatim copy; harness poisons d_out each call)
constexpr int NN = 8192;
constexpr int DD = 256;

typedef __bf16 bf16_t;
typedef __bf16 bf16x8 __attribute__((ext_vector_type(8)));
typedef __bf16 bf16x4 __attribute__((ext_vector_type(4)));
typedef float  floatx4 __attribute__((ext_vector_type(4)));

// ---------------------------------------------------------------------------
// K1: per-row degree + verbatim copy of A into out1. Pure streaming kernel.
// 8192 blocks x 256 threads; each block handles one 32KB row (8 float4/thread).
// ---------------------------------------------------------------------------
__global__ __launch_bounds__(256) void k1_deg_copy(const float* __restrict__ A,
                                                   float* __restrict__ Aout,
                                                   float* __restrict__ dvec) {
    const int row = blockIdx.x;
    const int t = threadIdx.x;
    const float4* __restrict__ src = (const float4*)(A + (size_t)row * NN);
    float4* __restrict__ dst = (float4*)(Aout + (size_t)row * NN);
    int cnt = 0;
#pragma unroll
    for (int i = 0; i < 8; ++i) {
        float4 v = src[t + 256 * i];
        dst[t + 256 * i] = v;
        cnt += (v.x > 1e-15f) + (v.y > 1e-15f) + (v.z > 1e-15f) + (v.w > 1e-15f);
    }
    // wave64 shuffle reduce, then cross-wave via LDS
#pragma unroll
    for (int off = 32; off > 0; off >>= 1) cnt += __shfl_down(cnt, off, 64);
    __shared__ int wsum[4];
    if ((t & 63) == 0) wsum[t >> 6] = cnt;
    __syncthreads();
    if (t == 0) {
        int total = wsum[0] + wsum[1] + wsum[2] + wsum[3];
        dvec[row] = rsqrtf(1.0f + (float)total);
    }
}

// load 8 consecutive fp32 and convert to a bf16x8 MFMA fragment
__device__ inline bf16x8 load_cvt8(const float* __restrict__ p) {
    float4 v0 = *(const float4*)p;
    float4 v1 = *(const float4*)(p + 4);
    bf16x8 r;
    r[0] = (bf16_t)v0.x; r[1] = (bf16_t)v0.y; r[2] = (bf16_t)v0.z; r[3] = (bf16_t)v0.w;
    r[4] = (bf16_t)v1.x; r[5] = (bf16_t)v1.y; r[6] = (bf16_t)v1.z; r[7] = (bf16_t)v1.w;
    return r;
}

// ---------------------------------------------------------------------------
// K2: H^T = W @ x^T via 16x16x32 bf16 MFMA.  M=256 (n), N=8192 (j), K=256.
// Writes gT[n][j] = d_j * h[j][n]  (bf16, k-contiguous rows for K3's B-frags)
// and    out[j][n] = d_j^2 * h[j][n]  (fp32; the A+I self-term, also serves as
// the accumulator init for K3's atomics).
// 256 blocks x 256 thr: block = 64 n x 128 j; wave w = 16 n x 128 j (8 tiles).
// A-frag (W) and B-frag (x) are direct global loads: both are k-contiguous.
// ---------------------------------------------------------------------------
__global__ __launch_bounds__(256) void k2_h_gt(const float* __restrict__ x,
                                               const float* __restrict__ W,
                                               const float* __restrict__ dvec,
                                               bf16_t* __restrict__ gT,
                                               float* __restrict__ out) {
    const int t = threadIdx.x;
    const int l = t & 63, w = t >> 6;
    const int lm = l & 15, q = l >> 4;
    const int nb = blockIdx.x & 3, jb = blockIdx.x >> 2;
    const int n0 = nb * 64 + w * 16;   // this wave's 16 n-rows
    const int j0 = jb * 128;

    floatx4 acc[8] = {};
#pragma unroll
    for (int kt = 0; kt < 256; kt += 32) {
        const int k = kt + q * 8;      // A/B frag: lane holds 8 consecutive k
        bf16x8 a = load_cvt8(W + (size_t)(n0 + lm) * DD + k);
#pragma unroll
        for (int jt = 0; jt < 8; ++jt) {
            bf16x8 b = load_cvt8(x + (size_t)(j0 + jt * 16 + lm) * DD + k);
            acc[jt] = __builtin_amdgcn_mfma_f32_16x16x32_bf16(a, b, acc[jt], 0, 0, 0);
        }
    }
    // C/D layout: col(j) = lane&15, row(n) = (lane>>4)*4 + reg   [m89-verified]
#pragma unroll
    for (int jt = 0; jt < 8; ++jt) {
        const int j = j0 + jt * 16 + lm;
        const float dj = dvec[j];
#pragma unroll
        for (int r = 0; r < 4; ++r) {
            const int n = n0 + q * 4 + r;
            const float hv = acc[jt][r];
            gT[(size_t)n * NN + j] = (bf16_t)(dj * hv);
            out[(size_t)j * DD + n] = dj * dj * hv;
        }
    }
}

// ---------------------------------------------------------------------------
// K3: P += (d_i*A) @ gT^T  (the 34.4 GFLOP GEMM), atomically into out.
// Grid 1024 = 256 m-tiles x 4 K-splits. Block = 32 m x 256 n x 2048 k.
// A (fp32) staged to LDS as bf16(d_i * A_ij); row stride 136 bf16 = 272 B
// (=17x16B: ds_read_b128-aligned, 4-bank row shift -> <=2-way conflicts).
// B-frags load 16B directly from gT (L2-resident, 4 MB).
// ---------------------------------------------------------------------------
__global__ __launch_bounds__(256) void k3_gemm(const float* __restrict__ A,
                                               const bf16_t* __restrict__ gT,
                                               const float* __restrict__ dvec,
                                               float* __restrict__ out) {
    __shared__ __align__(16) bf16_t As[32 * 136];
    __shared__ float sd[32];
    const int t = threadIdx.x;
    const int l = t & 63, w = t >> 6;
    const int lm = l & 15, q = l >> 4;
    const int mblk = blockIdx.x & 255, ks = blockIdx.x >> 8;
    const int m0 = mblk * 32;
    const int k0 = ks * 2048;

    if (t < 32) sd[t] = dvec[m0 + t];

    floatx4 acc[2][4] = {};
    for (int kt = 0; kt < 2048; kt += 128) {
        __syncthreads();  // also covers sd on first iter; protects As reuse after
        // stage 32x128 fp32 -> bf16(d_i*A) in LDS; 4 float4 per thread, coalesced
#pragma unroll
        for (int i = 0; i < 4; ++i) {
            const int f = t + 256 * i;         // 0..1023
            const int row = f >> 5, c4 = f & 31;
            float4 v = *(const float4*)(A + (size_t)(m0 + row) * NN + (k0 + kt) + c4 * 4);
            const float dm = sd[row];
            bf16x4 s;
            s[0] = (bf16_t)(v.x * dm); s[1] = (bf16_t)(v.y * dm);
            s[2] = (bf16_t)(v.z * dm); s[3] = (bf16_t)(v.w * dm);
            *(bf16x4*)(&As[row * 136 + c4 * 4]) = s;
        }
        __syncthreads();
#pragma unroll
        for (int kk = 0; kk < 128; kk += 32) {
            // A-frag: A[m = lane&15][k = (lane>>4)*8 + j], k-contiguous in LDS
            bf16x8 a0 = *(const bf16x8*)(&As[lm * 136 + kk + q * 8]);
            bf16x8 a1 = *(const bf16x8*)(&As[(16 + lm) * 136 + kk + q * 8]);
            const size_t kg = (size_t)(k0 + kt + kk + q * 8);
#pragma unroll
            for (int nt = 0; nt < 4; ++nt) {
                // B-frag: B[k][n = lane&15], k-contiguous row of gT
                bf16x8 b = *(const bf16x8*)(gT + (size_t)(w * 64 + nt * 16 + lm) * NN + kg);
                acc[0][nt] = __builtin_amdgcn_mfma_f32_16x16x32_bf16(a0, b, acc[0][nt], 0, 0, 0);
                acc[1][nt] = __builtin_amdgcn_mfma_f32_16x16x32_bf16(a1, b, acc[1][nt], 0, 0, 0);
            }
        }
    }
    // C/D: row(m) = q*4 + r (+16*mt), col(n) = lane&15. fp32 atomics merge K-splits.
#pragma unroll
    for (int mt = 0; mt < 2; ++mt)
#pragma unroll
        for (int nt = 0; nt < 4; ++nt)
#pragma unroll
            for (int r = 0; r < 4; ++r) {
                const int m = m0 + mt * 16 + q * 4 + r;
                const int n = w * 64 + nt * 16 + lm;
                atomicAdd(out + (size_t)m * DD + n, acc[mt][nt][r]);
            }
}

// ---------------------------------------------------------------------------
// K4: in-place relu over out0 (2M fp32, float4 per thread).
// ---------------------------------------------------------------------------
__global__ __launch_bounds__(256) void k4_relu(float* __restrict__ out) {
    const int idx = blockIdx.x * 256 + threadIdx.x;
    float4* p = (float4*)out;
    float4 v = p[idx];
    v.x = fmaxf(v.x, 0.f); v.y = fmaxf(v.y, 0.f);
    v.z = fmaxf(v.z, 0.f); v.w = fmaxf(v.w, 0.f);
    p[idx] = v;
}

extern "C" void kernel_launch(void* const* d_in, const int* in_sizes, int n_in,
                              void* d_out, int out_size, void* d_ws, size_t ws_size,
                              hipStream_t stream) {
    const float* x = (const float*)d_in[0];  // [8192,256]
    const float* A = (const float*)d_in[1];  // [8192,8192]
    const float* W = (const float*)d_in[2];  // [256,256]
    float* out0 = (float*)d_out;                     // [8192,256]
    float* out1 = out0 + (size_t)NN * DD;            // A copy [8192,8192]
    // ws layout: d[8192] fp32 (32KB) | gT[256][8192] bf16 (4MB)
    float* dvec = (float*)d_ws;
    bf16_t* gT = (bf16_t*)((char*)d_ws + 32768);

    k1_deg_copy<<<NN, 256, 0, stream>>>(A, out1, dvec);
    k2_h_gt<<<256, 256, 0, stream>>>(x, W, dvec, gT, out0);
    k3_gemm<<<1024, 256, 0, stream>>>(A, gT, dvec, out0);
    k4_relu<<<(NN * DD / 4) / 256, 256, 0, stream>>>(out0);
}

// Round 3
// 608.581 us; speedup vs baseline: 1.0268x; 1.0268x over previous
//
#include <hip/hip_runtime.h>
#include <hip/hip_bf16.h>

// Problem: N=8192 nodes, DIN=DOUT=256.
// out0 = relu( diag(d) (A+I) diag(d) (x @ W^T) ),  d_i = rsqrt(1 + #(A_ij>eps))
// out1 = A (verbatim copy; harness poisons d_out each call)
constexpr int NN = 8192;
constexpr int DD = 256;

typedef __bf16 bf16_t;
typedef __bf16 bf16x8 __attribute__((ext_vector_type(8)));
typedef float  floatx4 __attribute__((ext_vector_type(4)));  // native vec (nontemporal-ok)

#define GLOBAL_AS __attribute__((address_space(1)))
#define LDS_AS    __attribute__((address_space(3)))

// ---------------------------------------------------------------------------
// K1: per-row degree + verbatim copy of A into out1. Pure streaming.
// Nontemporal stores: don't let the copy evict A from L3 (k3 re-reads A).
// ---------------------------------------------------------------------------
__global__ __launch_bounds__(256) void k1_deg_copy(const float* __restrict__ A,
                                                   float* __restrict__ Aout,
                                                   float* __restrict__ dvec) {
    const int row = blockIdx.x;
    const int t = threadIdx.x;
    const floatx4* __restrict__ src = (const floatx4*)(A + (size_t)row * NN);
    floatx4* __restrict__ dst = (floatx4*)(Aout + (size_t)row * NN);
    int cnt = 0;
#pragma unroll
    for (int i = 0; i < 8; ++i) {
        floatx4 v = src[t + 256 * i];
        __builtin_nontemporal_store(v, &dst[t + 256 * i]);
        cnt += (v.x > 1e-15f) + (v.y > 1e-15f) + (v.z > 1e-15f) + (v.w > 1e-15f);
    }
#pragma unroll
    for (int off = 32; off > 0; off >>= 1) cnt += __shfl_down(cnt, off, 64);
    __shared__ int wsum[4];
    if ((t & 63) == 0) wsum[t >> 6] = cnt;
    __syncthreads();
    if (t == 0) {
        int total = wsum[0] + wsum[1] + wsum[2] + wsum[3];
        dvec[row] = rsqrtf(1.0f + (float)total);
    }
}

// load 8 consecutive fp32 and convert to a bf16x8 MFMA fragment
__device__ inline bf16x8 load_cvt8(const float* __restrict__ p) {
    floatx4 v0 = *(const floatx4*)p;
    floatx4 v1 = *(const floatx4*)(p + 4);
    bf16x8 r;
    r[0] = (bf16_t)v0.x; r[1] = (bf16_t)v0.y; r[2] = (bf16_t)v0.z; r[3] = (bf16_t)v0.w;
    r[4] = (bf16_t)v1.x; r[5] = (bf16_t)v1.y; r[6] = (bf16_t)v1.z; r[7] = (bf16_t)v1.w;
    return r;
}

// ---------------------------------------------------------------------------
// K2: H^T = W @ x^T via 16x16x32 bf16 MFMA.  M=256 (n), N=8192 (j), K=256.
// gT[n][j] = d_j * h[j][n]  (bf16, k-contiguous for K3 B-frags)
// out[j][n] = d_j^2 * h[j][n] (the A+I self-term = K3's accumulator init).
// Grid 512: block = 64 n x 64 j (2 blocks/CU for latency hiding).
// ---------------------------------------------------------------------------
__global__ __launch_bounds__(256) void k2_h_gt(const float* __restrict__ x,
                                               const float* __restrict__ W,
                                               const float* __restrict__ dvec,
                                               bf16_t* __restrict__ gT,
                                               float* __restrict__ out) {
    const int t = threadIdx.x;
    const int l = t & 63, w = t >> 6;
    const int lm = l & 15, q = l >> 4;
    const int nb = blockIdx.x & 3, jb = blockIdx.x >> 2;
    const int n0 = nb * 64 + w * 16;
    const int j0 = jb * 64;

    floatx4 acc[4] = {};
#pragma unroll
    for (int kt = 0; kt < 256; kt += 32) {
        const int k = kt + q * 8;
        bf16x8 a = load_cvt8(W + (size_t)(n0 + lm) * DD + k);
#pragma unroll
        for (int jt = 0; jt < 4; ++jt) {
            bf16x8 b = load_cvt8(x + (size_t)(j0 + jt * 16 + lm) * DD + k);
            acc[jt] = __builtin_amdgcn_mfma_f32_16x16x32_bf16(a, b, acc[jt], 0, 0, 0);
        }
    }
    // C/D layout: col(j) = lane&15, row(n) = (lane>>4)*4 + reg   [m89-verified]
#pragma unroll
    for (int jt = 0; jt < 4; ++jt) {
        const int j = j0 + jt * 16 + lm;
        const float dj = dvec[j];
#pragma unroll
        for (int r = 0; r < 4; ++r) {
            const int n = n0 + q * 4 + r;
            const float hv = acc[jt][r];
            gT[(size_t)n * NN + j] = (bf16_t)(dj * hv);
            out[(size_t)j * DD + n] = dj * dj * hv;
        }
    }
}

// ---------------------------------------------------------------------------
// K3: out += diag(d) * (A @ gT^T), atomically (fp32), then K4 applies relu.
// Grid 1024 = 128 m-tiles (BM=64) x 8 K-splits (1024 k each). 256 thr.
// A staged raw-fp32 via async global_load_lds (16B), double-buffered 2x16KB.
// LDS layout XOR-swizzled by row (padding impossible with global_load_lds:
// dest is wave-uniform base + lane*16 [m104/m108]); swizzle keeps frag reads
// uniformly bank-distributed. d_i applied in epilogue (algebraic move).
// B-frags load 16B direct from gT (L2-resident 4MB; 512MB total traffic).
// ---------------------------------------------------------------------------
__global__ __launch_bounds__(256, 3) void k3_gemm(const float* __restrict__ A,
                                                  const bf16_t* __restrict__ gT,
                                                  const float* __restrict__ dvec,
                                                  float* __restrict__ out) {
    __shared__ __align__(16) float As[2][64 * 64];  // 2 x 16KB, fp32, swizzled
    __shared__ float sd[64];
    const int t = threadIdx.x;
    const int l = t & 63, w = t >> 6;
    const int lm = l & 15, q = l >> 4;
    const int mblk = blockIdx.x & 127, ks = blockIdx.x >> 7;
    const int m0 = mblk * 64;
    const int k0 = ks * 1024;

    if (t < 64) sd[t] = dvec[m0 + t];

    // async stage of one 64x64 fp32 chunk: 1024 16B-units, 4 issues/thread.
    // phys unit p = j*256 + t -> holds A[m0 + p>>4][kc + ((p&15) ^ ((p>>4)&15))*4 ..+4)
    auto stage = [&](const float* Abase, int kc, float* buf) {
#pragma unroll
        for (int j = 0; j < 4; ++j) {
            const int p = j * 256 + t;
            const int m = p >> 4;
            const int klog = (p & 15) ^ (m & 15);
            const float* src = Abase + (size_t)(m0 + m) * NN + kc + klog * 4;
            float* ldsb = buf + (size_t)(j * 256 + w * 64) * 4;  // wave-uniform
            __builtin_amdgcn_global_load_lds((const GLOBAL_AS void*)src,
                                             (LDS_AS void*)ldsb, 16, 0, 0);
        }
    };
    // read bf16 A-frag for row m, fp32-unit u0 (=kk/4 + 2q), swizzle-aware
    auto read_a = [&](const float* buf, int m, int u0) -> bf16x8 {
        const int s = m & 15;
        const floatx4 f0 = *(const floatx4*)(buf + (size_t)(m * 16 + (u0 ^ s)) * 4);
        const floatx4 f1 = *(const floatx4*)(buf + (size_t)(m * 16 + ((u0 + 1) ^ s)) * 4);
        bf16x8 r;
        r[0] = (bf16_t)f0.x; r[1] = (bf16_t)f0.y; r[2] = (bf16_t)f0.z; r[3] = (bf16_t)f0.w;
        r[4] = (bf16_t)f1.x; r[5] = (bf16_t)f1.y; r[6] = (bf16_t)f1.z; r[7] = (bf16_t)f1.w;
        return r;
    };

    floatx4 acc[4][4] = {};  // [mt][nt], wave w covers n = w*64 .. +63
    const bf16_t* gb = gT + (size_t)(w * 64 + lm) * NN + k0 + q * 8;

    stage(A, k0, As[0]);
    __syncthreads();  // drains vmcnt(0): chunk 0 resident
    for (int c = 0; c < 16; ++c) {
        if (c + 1 < 16) stage(A, k0 + (c + 1) * 64, As[(c + 1) & 1]);  // async
        const float* buf = As[c & 1];
#pragma unroll
        for (int kk = 0; kk < 64; kk += 32) {
            const size_t kg = (size_t)(c * 64 + kk);
            bf16x8 b0 = *(const bf16x8*)(gb + 0 * 16 * NN + kg);
            bf16x8 b1 = *(const bf16x8*)(gb + 1 * 16 * NN + kg);
            bf16x8 b2 = *(const bf16x8*)(gb + 2 * 16 * NN + kg);
            bf16x8 b3 = *(const bf16x8*)(gb + 3 * 16 * NN + kg);
            const int u0 = (kk >> 2) + 2 * q;
            bf16x8 a0 = read_a(buf, 0 * 16 + lm, u0);
            bf16x8 a1 = read_a(buf, 1 * 16 + lm, u0);
            bf16x8 a2 = read_a(buf, 2 * 16 + lm, u0);
            bf16x8 a3 = read_a(buf, 3 * 16 + lm, u0);
            acc[0][0] = __builtin_amdgcn_mfma_f32_16x16x32_bf16(a0, b0, acc[0][0], 0, 0, 0);
            acc[0][1] = __builtin_amdgcn_mfma_f32_16x16x32_bf16(a0, b1, acc[0][1], 0, 0, 0);
            acc[0][2] = __builtin_amdgcn_mfma_f32_16x16x32_bf16(a0, b2, acc[0][2], 0, 0, 0);
            acc[0][3] = __builtin_amdgcn_mfma_f32_16x16x32_bf16(a0, b3, acc[0][3], 0, 0, 0);
            acc[1][0] = __builtin_amdgcn_mfma_f32_16x16x32_bf16(a1, b0, acc[1][0], 0, 0, 0);
            acc[1][1] = __builtin_amdgcn_mfma_f32_16x16x32_bf16(a1, b1, acc[1][1], 0, 0, 0);
            acc[1][2] = __builtin_amdgcn_mfma_f32_16x16x32_bf16(a1, b2, acc[1][2], 0, 0, 0);
            acc[1][3] = __builtin_amdgcn_mfma_f32_16x16x32_bf16(a1, b3, acc[1][3], 0, 0, 0);
            acc[2][0] = __builtin_amdgcn_mfma_f32_16x16x32_bf16(a2, b0, acc[2][0], 0, 0, 0);
            acc[2][1] = __builtin_amdgcn_mfma_f32_16x16x32_bf16(a2, b1, acc[2][1], 0, 0, 0);
            acc[2][2] = __builtin_amdgcn_mfma_f32_16x16x32_bf16(a2, b2, acc[2][2], 0, 0, 0);
            acc[2][3] = __builtin_amdgcn_mfma_f32_16x16x32_bf16(a2, b3, acc[2][3], 0, 0, 0);
            acc[3][0] = __builtin_amdgcn_mfma_f32_16x16x32_bf16(a3, b0, acc[3][0], 0, 0, 0);
            acc[3][1] = __builtin_amdgcn_mfma_f32_16x16x32_bf16(a3, b1, acc[3][1], 0, 0, 0);
            acc[3][2] = __builtin_amdgcn_mfma_f32_16x16x32_bf16(a3, b2, acc[3][2], 0, 0, 0);
            acc[3][3] = __builtin_amdgcn_mfma_f32_16x16x32_bf16(a3, b3, acc[3][3], 0, 0, 0);
        }
        __syncthreads();  // vmcnt drain -> chunk c+1 resident; LDS reads done
    }
    // C/D: row(m) = q*4 + r (+16*mt), col(n) = lane&15. d_m applied here.
#pragma unroll
    for (int mt = 0; mt < 4; ++mt)
#pragma unroll
        for (int r = 0; r < 4; ++r) {
            const int mrow = mt * 16 + q * 4 + r;
            const float dm = sd[mrow];
            const int m = m0 + mrow;
#pragma unroll
            for (int nt = 0; nt < 4; ++nt) {
                const int n = w * 64 + nt * 16 + lm;
                atomicAdd(out + (size_t)m * DD + n, dm * acc[mt][nt][r]);
            }
        }
}

// ---------------------------------------------------------------------------
// K4: in-place relu over out0 (2M fp32, float4 per thread).
// ---------------------------------------------------------------------------
__global__ __launch_bounds__(256) void k4_relu(float* __restrict__ out) {
    const int idx = blockIdx.x * 256 + threadIdx.x;
    floatx4* p = (floatx4*)out;
    floatx4 v = p[idx];
    v.x = fmaxf(v.x, 0.f); v.y = fmaxf(v.y, 0.f);
    v.z = fmaxf(v.z, 0.f); v.w = fmaxf(v.w, 0.f);
    p[idx] = v;
}

extern "C" void kernel_launch(void* const* d_in, const int* in_sizes, int n_in,
                              void* d_out, int out_size, void* d_ws, size_t ws_size,
                              hipStream_t stream) {
    const float* x = (const float*)d_in[0];  // [8192,256]
    const float* A = (const float*)d_in[1];  // [8192,8192]
    const float* W = (const float*)d_in[2];  // [256,256]
    float* out0 = (float*)d_out;                     // [8192,256]
    float* out1 = out0 + (size_t)NN * DD;            // A copy [8192,8192]
    float* dvec = (float*)d_ws;                      // 32KB
    bf16_t* gT = (bf16_t*)((char*)d_ws + 32768);     // 4MB

    k1_deg_copy<<<NN, 256, 0, stream>>>(A, out1, dvec);
    k2_h_gt<<<512, 256, 0, stream>>>(x, W, dvec, gT, out0);
    k3_gemm<<<1024, 256, 0, stream>>>(A, gT, dvec, out0);
    k4_relu<<<(NN * DD / 4) / 256, 256, 0, stream>>>(out0);
}